// Round 17
// baseline (385.027 us; speedup 1.0000x reference)
//
#include <hip/hip_runtime.h>
#include <cstdint>
#include <cstddef>

#define AS1 __attribute__((address_space(1)))
#define AS3 __attribute__((address_space(3)))

typedef __attribute__((ext_vector_type(8))) short bf16x8;
typedef __attribute__((ext_vector_type(4))) short short4v;
typedef __attribute__((ext_vector_type(8))) unsigned short u16x8;
typedef __attribute__((ext_vector_type(4))) float f32x4;
typedef __attribute__((ext_vector_type(4))) unsigned short u16x4;

__device__ __forceinline__ float b2f(uint16_t u){ return __uint_as_float(((uint32_t)u) << 16); }
__device__ __forceinline__ uint16_t f2b(float f){
    uint32_t u = __float_as_uint(f);
    return (uint16_t)((u + 0x7fffu + ((u >> 16) & 1u)) >> 16);
}

// window-order row r  ->  pixel index (window reverse + unshift / shift+partition gather)
__device__ __forceinline__ int pixof(int r){
    int w  = r / 49, t = r - w * 49;
    int wh = w >> 5, ww = w & 31;
    int th = t / 7,  tw = t - th * 7;
    int hp = wh * 7 + th + 3; if (hp >= 224) hp -= 224;
    int wp = ww * 7 + tw + 3; if (wp >= 224) wp -= 224;
    return hp * 224 + wp;
}

// --- init über-kernel: weights fp32->bf16 (blocks 0..6911), bias/mask table
// (6912..6959), LN1+shift+window-partition (6960..19503) -------------------
__global__ __launch_bounds__(256) void init_kernel(
        const float* __restrict__ a0, const float* __restrict__ a1,
        const float* __restrict__ a2, const float* __restrict__ a3,
        uint16_t* __restrict__ o0, uint16_t* __restrict__ o1,
        uint16_t* __restrict__ o2, uint16_t* __restrict__ o3,
        const float* __restrict__ rpb, float* __restrict__ bm,
        const float* __restrict__ x, const float* __restrict__ n1w,
        const float* __restrict__ n1b, uint16_t* __restrict__ win){
    int b = blockIdx.x;
    if (b >= 6960){
        int wave = threadIdx.x >> 6, lane = threadIdx.x & 63;
        int r = (b - 6960) * 4 + wave;
        const float* row = x + (size_t)pixof(r) * 384;
        float a[6];
        #pragma unroll
        for (int i = 0; i < 6; ++i) a[i] = row[lane * 6 + i];
        float s = 0.f, q = 0.f;
        #pragma unroll
        for (int i = 0; i < 6; ++i){ s += a[i]; q += a[i] * a[i]; }
        #pragma unroll
        for (int o = 32; o; o >>= 1){ s += __shfl_xor(s, o); q += __shfl_xor(q, o); }
        float mu   = s * (1.f / 384.f);
        float var  = q * (1.f / 384.f) - mu * mu;
        float rstd = rsqrtf(var + 1e-5f);
        uint16_t* orow = win + (size_t)r * 384;
        #pragma unroll
        for (int i = 0; i < 6; ++i){
            int c = lane * 6 + i;
            orow[c] = f2b((a[i] - mu) * rstd * n1w[c] + n1b[c]);
        }
        return;
    }
    if (b >= 6912){
        int th = b - 6912;                // 0..47 = type*12 + h
        int type = th / 12, h = th - (th / 12) * 12;
        int eh = type >> 1, ew = type & 1;
        for (int idx = threadIdx.x; idx < 4096; idx += 256){
            int q = idx >> 6, kt = idx & 63;
            float v = 0.f;
            if (q < 49 && kt < 49){
                int ih = q / 7,  iw = q - 7 * (q / 7);
                int jh = kt / 7, jw = kt - 7 * (kt / 7);
                v = rpb[((ih - jh + 6) * 13 + (iw - jw + 6)) * 12 + h];
                int ri = (eh ? (ih < 4 ? 1 : 2) : 0) * 3 + (ew ? (iw < 4 ? 1 : 2) : 0);
                int rj = (eh ? (jh < 4 ? 1 : 2) : 0) * 3 + (ew ? (jw < 4 ? 1 : 2) : 0);
                if (ri != rj) v -= 100.f;
            }
            bm[(size_t)th * 4096 + idx] = v;
        }
        return;
    }
    const float* src; uint16_t* dst; int base;
    if (b < 1728)      { src = a0; dst = o0; base = b; }
    else if (b < 2304) { src = a1; dst = o1; base = b - 1728; }
    else if (b < 4608) { src = a2; dst = o2; base = b - 2304; }
    else               { src = a3; dst = o3; base = b - 4608; }
    int i = base * 256 + threadIdx.x;
    dst[i] = f2b(src[i]);
}

// ---------------- LN2: bf16 in (vectorized u16x8, 48 active lanes) -> bf16 -----
__global__ __launch_bounds__(256) void ln2_kernel(const uint16_t* __restrict__ in,
        const float* __restrict__ g, const float* __restrict__ b, uint16_t* __restrict__ out){
    int wave = threadIdx.x >> 6, lane = threadIdx.x & 63;
    int r = blockIdx.x * 4 + wave;
    u16x8 v8 = {0,0,0,0,0,0,0,0};
    if (lane < 48) v8 = *(const u16x8*)(in + (size_t)r * 384 + lane * 8);
    float a[8];
    float s = 0.f, q = 0.f;
    #pragma unroll
    for (int i = 0; i < 8; ++i){ a[i] = b2f(v8[i]); s += a[i]; q += a[i] * a[i]; }
    #pragma unroll
    for (int o = 32; o; o >>= 1){ s += __shfl_xor(s, o); q += __shfl_xor(q, o); }
    float mu   = s * (1.f / 384.f);
    float var  = q * (1.f / 384.f) - mu * mu;
    float rstd = rsqrtf(var + 1e-5f);
    if (lane < 48){
        u16x8 o8;
        #pragma unroll
        for (int i = 0; i < 8; ++i){
            int c = lane * 8 + i;
            o8[i] = f2b((a[i] - mu) * rstd * g[c] + b[c]);
        }
        *(u16x8*)(out + (size_t)r * 384 + lane * 8) = o8;
    }
}

// ---------------- GEMM: C = A(MxK) * B(NxK)^T + bias, BK=128 single-buffer ------
// 128x128 tile, 4 waves (2x2), per-wave 4x4 16x16 frags, K-step 128:
// 16 global_load_lds + 1 barrier-pair per 64 MFMAs (half the drains of BK=64).
// LDS rows are 256 B with 16-slot XOR swizzle (2-way banks = free), staged via
// lane-pure pre-swizzled global source (rule #21). 64 KB LDS, 2 blocks/CU
// (unchanged: launch_bounds cap was already 2).
// EPI 1: bf16 out + exact GELU (fc1).
// EPI 5: bf16 out natural [row][N], cols<384 scaled (qkv).
// EPI 6: bf16 x2 out, pixof-permuted, + fp32 shortcut xres (proj).
// EPI 7: fp32 out = bf16 x2b + acc + bias, write-only (fc2 final).
template<int EPI>
__global__ __launch_bounds__(256, 2) void gemm_bt(
        const uint16_t* __restrict__ A, const uint16_t* __restrict__ B,
        const float* __restrict__ bias, void* __restrict__ outp,
        const float* __restrict__ xres, const uint16_t* __restrict__ xb,
        int N, int K, int row0)
{
    __shared__ alignas(16) uint16_t lA[128 * 128];
    __shared__ alignas(16) uint16_t lB[128 * 128];
    int tid  = threadIdx.x;
    int lane = tid & 63, wave = tid >> 6;

    // XCD-chunked bijective swizzle: same-bm tiles land on one XCD (A-panel L2 reuse)
    int nwg = gridDim.x, bid = blockIdx.x;
    int q8 = nwg >> 3, r8 = nwg & 7;
    int xcd = bid & 7, idx = bid >> 3;
    int wg = (xcd < r8 ? xcd * (q8 + 1) : r8 * (q8 + 1) + (xcd - r8) * q8) + idx;

    int nt = N >> 7;
    int bm = wg / nt, bn = wg - bm * nt;
    int wr = wave >> 1, wc = wave & 1;
    int fr = lane & 15, kc = lane >> 4;

    // staging: wave covers 32 rows in 8 instrs of 4 rows x 16 slots;
    // slot s = lane&15 holds global col-chunk s ^ (row&15)
    int lr = lane >> 4, sl = lane & 15;
    const uint16_t* gAr = A + (size_t)(bm * 128 + wave * 32 + lr) * K;
    const uint16_t* gBr = B + (size_t)(bn * 128 + wave * 32 + lr) * K;

    // compute-read byte offsets (within 256 B row, XOR by (row&15)<<4): 2-way banks
    int aoff[4], boff[4];
    #pragma unroll
    for (int m = 0; m < 4; ++m){
        int row = wr * 64 + m * 16 + fr;
        aoff[m] = row * 256 + ((kc * 16) ^ ((row & 15) << 4));
        int rowB = wc * 64 + m * 16 + fr;
        boff[m] = rowB * 256 + ((kc * 16) ^ ((rowB & 15) << 4));
    }

    f32x4 acc[4][4] = {};
    const int NT = K >> 7;
    for (int t = 0; t < NT; ++t){
        int k0 = t << 7;
        #pragma unroll
        for (int it = 0; it < 8; ++it){
            int cs = sl ^ ((it * 4 + lr) & 15);
            __builtin_amdgcn_global_load_lds((const AS1 void*)(gAr + (size_t)(it * 4) * K + k0 + cs * 8),
                (AS3 void*)((AS3 char*)lA + wave * 8192 + it * 1024), 16, 0, 0);
            __builtin_amdgcn_global_load_lds((const AS1 void*)(gBr + (size_t)(it * 4) * K + k0 + cs * 8),
                (AS3 void*)((AS3 char*)lB + wave * 8192 + it * 1024), 16, 0, 0);
        }
        __syncthreads();

        #pragma unroll
        for (int ks = 0; ks < 4; ++ks){
            bf16x8 af[4], bv[4];
            #pragma unroll
            for (int m = 0; m < 4; ++m)
                af[m] = *(const bf16x8*)((const char*)lA + (aoff[m] ^ (ks << 6)));
            #pragma unroll
            for (int n = 0; n < 4; ++n)
                bv[n] = *(const bf16x8*)((const char*)lB + (boff[n] ^ (ks << 6)));
            #pragma unroll
            for (int m = 0; m < 4; ++m)
                #pragma unroll
                for (int n = 0; n < 4; ++n)
                    acc[m][n] = __builtin_amdgcn_mfma_f32_16x16x32_bf16(af[m], bv[n], acc[m][n], 0, 0, 0);
        }
        __syncthreads();
    }

    int colb = bn * 128 + wc * 64 + fr;
    int rowb = bm * 128 + wr * 64 + ((lane >> 4) << 2);
    float bvv[4];
    #pragma unroll
    for (int n = 0; n < 4; ++n) bvv[n] = bias[colb + n * 16];

    if constexpr (EPI == 1 || EPI == 5){
        uint16_t* out = (uint16_t*)outp;
        #pragma unroll
        for (int m = 0; m < 4; ++m)
            #pragma unroll
            for (int rg = 0; rg < 4; ++rg){
                size_t rr = (size_t)(rowb + m * 16 + rg) * N;
                #pragma unroll
                for (int n = 0; n < 4; ++n){
                    int col = colb + n * 16;
                    float v = acc[m][n][rg] + bvv[n];
                    if constexpr (EPI == 1) v = 0.5f * v * (1.f + erff(v * 0.7071067811865475f));
                    if constexpr (EPI == 5){ if (col < 384) v *= 0.1767766952966369f; }
                    out[rr + col] = f2b(v);
                }
            }
    } else if constexpr (EPI == 6){
        uint16_t* out = (uint16_t*)outp;
        #pragma unroll
        for (int m = 0; m < 4; ++m)
            #pragma unroll
            for (int rg = 0; rg < 4; ++rg){
                int r = row0 + rowb + m * 16 + rg;
                size_t pb = (size_t)pixof(r) * 384;
                #pragma unroll
                for (int n = 0; n < 4; ++n){
                    int c = colb + n * 16;
                    out[pb + c] = f2b(xres[pb + c] + acc[m][n][rg] + bvv[n]);
                }
            }
    } else { // EPI == 7
        float* out = (float*)outp;
        #pragma unroll
        for (int m = 0; m < 4; ++m)
            #pragma unroll
            for (int rg = 0; rg < 4; ++rg){
                size_t rb2 = (size_t)(rowb + m * 16 + rg) * 384;
                #pragma unroll
                for (int n = 0; n < 4; ++n){
                    int c = colb + n * 16;
                    out[rb2 + c] = b2f(xb[rb2 + c]) + acc[m][n][rg] + bvv[n];
                }
            }
    }
}

// ------- fc2 GEMM: 64x128 tile, BK=128 (12 barrier-pairs for K=1536) ------------
// 4 waves as 1M x 4N strips: wave = rows[0:64] x cols[wave*32 : wave*32+32],
// acc[4][2]. Same 256B-row / 16-slot XOR mechanics as gemm_bt.
// out fp32 = bf16 xb + acc + bias (write-only d_out).
__global__ __launch_bounds__(256, 2) void gemm_fc2(
        const uint16_t* __restrict__ A, const uint16_t* __restrict__ B,
        const float* __restrict__ bias, float* __restrict__ out,
        const uint16_t* __restrict__ xb, int K)
{
    __shared__ alignas(16) uint16_t lA[64 * 128];
    __shared__ alignas(16) uint16_t lB[128 * 128];
    int tid  = threadIdx.x;
    int lane = tid & 63, wave = tid >> 6;

    int nwg = gridDim.x, bid = blockIdx.x;
    int q8 = nwg >> 3, r8 = nwg & 7;
    int xcd = bid & 7, idx = bid >> 3;
    int wg = (xcd < r8 ? xcd * (q8 + 1) : r8 * (q8 + 1) + (xcd - r8) * q8) + idx;

    int bm = wg / 3, bn = wg - bm * 3;    // N = 384 -> 3 col-tiles of 128
    int fr = lane & 15, kc = lane >> 4;

    int lr = lane >> 4, sl = lane & 15;
    const uint16_t* gAr = A + (size_t)(bm * 64 + wave * 16 + lr) * K;
    const uint16_t* gBr = B + (size_t)(bn * 128 + wave * 32 + lr) * K;

    int aoff[4], boff[2];
    #pragma unroll
    for (int m = 0; m < 4; ++m){
        int row = m * 16 + fr;
        aoff[m] = row * 256 + ((kc * 16) ^ ((row & 15) << 4));
    }
    #pragma unroll
    for (int n = 0; n < 2; ++n){
        int rowB = wave * 32 + n * 16 + fr;
        boff[n] = rowB * 256 + ((kc * 16) ^ ((rowB & 15) << 4));
    }

    f32x4 acc[4][2] = {};
    const int NT = K >> 7;
    for (int t = 0; t < NT; ++t){
        int k0 = t << 7;
        #pragma unroll
        for (int it = 0; it < 4; ++it){
            int cs = sl ^ ((it * 4 + lr) & 15);
            __builtin_amdgcn_global_load_lds((const AS1 void*)(gAr + (size_t)(it * 4) * K + k0 + cs * 8),
                (AS3 void*)((AS3 char*)lA + wave * 4096 + it * 1024), 16, 0, 0);
        }
        #pragma unroll
        for (int it = 0; it < 8; ++it){
            int cs = sl ^ ((it * 4 + lr) & 15);
            __builtin_amdgcn_global_load_lds((const AS1 void*)(gBr + (size_t)(it * 4) * K + k0 + cs * 8),
                (AS3 void*)((AS3 char*)lB + wave * 8192 + it * 1024), 16, 0, 0);
        }
        __syncthreads();

        #pragma unroll
        for (int ks = 0; ks < 4; ++ks){
            bf16x8 af[4], bv[2];
            #pragma unroll
            for (int m = 0; m < 4; ++m)
                af[m] = *(const bf16x8*)((const char*)lA + (aoff[m] ^ (ks << 6)));
            #pragma unroll
            for (int n = 0; n < 2; ++n)
                bv[n] = *(const bf16x8*)((const char*)lB + (boff[n] ^ (ks << 6)));
            #pragma unroll
            for (int m = 0; m < 4; ++m)
                #pragma unroll
                for (int n = 0; n < 2; ++n)
                    acc[m][n] = __builtin_amdgcn_mfma_f32_16x16x32_bf16(af[m], bv[n], acc[m][n], 0, 0, 0);
        }
        __syncthreads();
    }

    int colb = bn * 128 + wave * 32 + fr;
    int rowb = bm * 64 + kc * 4;
    float bvv[2] = { bias[colb], bias[colb + 16] };
    #pragma unroll
    for (int m = 0; m < 4; ++m)
        #pragma unroll
        for (int rg = 0; rg < 4; ++rg){
            size_t rb2 = (size_t)(rowb + m * 16 + rg) * 384;
            #pragma unroll
            for (int n = 0; n < 2; ++n){
                int c = colb + n * 16;
                out[rb2 + c] = b2f(xb[rb2 + c]) + acc[m][n][rg] + bvv[n];
            }
        }
}

// ---------------- MFMA windowed attention: one wave per (window, head) ----------------
// qkv: [50176][1152] bf16, q pre-scaled.  bm: bias+mask table (C-operand of QK^T).
// V: global -> regs (early, T14) -> scalar-transpose LDS [32][68] -> b64 row reads.
__global__ __launch_bounds__(256) void attn_mfma(const uint16_t* __restrict__ qkv,
        const float* __restrict__ bm, uint16_t* __restrict__ out)
{
    __shared__ uint16_t vtl[4][32][68];   // [d][t] padded t->68 (odd 8B stride: 4-way-free b64 reads)
    int wv = threadIdx.x >> 6, lane = threadIdx.x & 63;
    int p = blockIdx.x * 4 + wv;
    int w = p / 12, h = p - w * 12;
    int c = lane & 15, g = lane >> 4;
    const uint16_t* base = qkv + (size_t)(w * 49) * 1152 + h * 32;

    // V global loads issued early (T14 async split)
    u16x8 vreg[4];
    #pragma unroll
    for (int it = 0; it < 4; ++it){
        int u = it * 64 + lane;           // u = t*4 + dq
        int t = u >> 2, dq = u & 3;
        u16x8 v8 = {0,0,0,0,0,0,0,0};
        if (t < 49) v8 = *(const u16x8*)(base + (size_t)t * 1152 + 768 + dq * 8);
        vreg[it] = v8;
    }

    // Q (B-frag) and K (A-frag): 16B contiguous per lane
    bf16x8 qf[4], kf[4];
    #pragma unroll
    for (int nt = 0; nt < 4; ++nt) qf[nt] = *(const bf16x8*)(base + (size_t)(16 * nt + c) * 1152 + g * 8);
    #pragma unroll
    for (int mt = 0; mt < 4; ++mt) kf[mt] = *(const bf16x8*)(base + (size_t)(16 * mt + c) * 1152 + 384 + g * 8);

    // S^T = K * Q^T + biasmask(C-operand): row = kt = 16mt+4g+r, col = q = 16nt+c
    int wh = w >> 5, ww = w & 31;
    int type = ((wh == 31) << 1) | (ww == 31);
    const float* bmp = bm + (size_t)(type * 12 + h) * 4096;
    f32x4 sv[4][4];
    __builtin_amdgcn_s_setprio(1);
    #pragma unroll
    for (int mt = 0; mt < 4; ++mt)
        #pragma unroll
        for (int nt = 0; nt < 4; ++nt){
            f32x4 cb = *(const f32x4*)(bmp + (16 * nt + c) * 64 + 16 * mt + 4 * g);
            sv[mt][nt] = __builtin_amdgcn_mfma_f32_16x16x32_bf16(kf[mt], qf[nt], cb, 0, 0, 0);
        }
    __builtin_amdgcn_s_setprio(0);

    // V -> LDS scalar transpose (proven path)
    #pragma unroll
    for (int it = 0; it < 4; ++it){
        int u = it * 64 + lane;
        int t = u >> 2, dq = u & 3;
        #pragma unroll
        for (int j = 0; j < 8; ++j) vtl[wv][dq * 8 + j][t] = vreg[it][j];
    }

    // kt >= 49 mask (only mt=3 rows: kt = 48+4g+r)
    #pragma unroll
    for (int nt = 0; nt < 4; ++nt)
        #pragma unroll
        for (int r = 0; r < 4; ++r)
            if (4 * g + r >= 1) sv[3][nt][r] = -1e9f;

    // softmax over kt (rows of S^T)
    float inv[4];
    #pragma unroll
    for (int nt = 0; nt < 4; ++nt){
        float mx = -1e30f;
        #pragma unroll
        for (int mt = 0; mt < 4; ++mt)
            #pragma unroll
            for (int r = 0; r < 4; ++r) mx = fmaxf(mx, sv[mt][nt][r]);
        mx = fmaxf(mx, __shfl_xor(mx, 16));
        mx = fmaxf(mx, __shfl_xor(mx, 32));
        float sum = 0.f;
        #pragma unroll
        for (int mt = 0; mt < 4; ++mt)
            #pragma unroll
            for (int r = 0; r < 4; ++r){
                float e = __expf(sv[mt][nt][r] - mx);
                sv[mt][nt][r] = e; sum += e;
            }
        sum += __shfl_xor(sum, 16);
        sum += __shfl_xor(sum, 32);
        inv[nt] = 1.f / sum;
    }

    // pack P to bf16 pairs
    unsigned pk[4][4][2];
    #pragma unroll
    for (int nt = 0; nt < 4; ++nt)
        #pragma unroll
        for (int mt = 0; mt < 4; ++mt)
            #pragma unroll
            for (int pr = 0; pr < 2; ++pr)
                pk[nt][mt][pr] = (unsigned)f2b(sv[mt][nt][2 * pr]) |
                                 ((unsigned)f2b(sv[mt][nt][2 * pr + 1]) << 16);

    // relayout P^T(C-layout) -> B-frags via ds_bpermute
    int a0 = (c + 16 * (2 * (g & 1))) * 4;
    int a1 = a0 + 64;
    int sel = g >> 1;

    f32x4 acco[2][4] = {};
    #pragma unroll
    for (int ks = 0; ks < 2; ++ks){
        bf16x8 va[2];
        #pragma unroll
        for (int mt = 0; mt < 2; ++mt){
            short4v lo = *(const short4v*)&vtl[wv][mt * 16 + c][ks * 32 + g * 8];
            short4v hi = *(const short4v*)&vtl[wv][mt * 16 + c][ks * 32 + g * 8 + 4];
            bf16x8 t;
            t[0] = lo[0]; t[1] = lo[1]; t[2] = lo[2]; t[3] = lo[3];
            t[4] = hi[0]; t[5] = hi[1]; t[6] = hi[2]; t[7] = hi[3];
            va[mt] = t;
        }
        bf16x8 pb[4];
        #pragma unroll
        for (int nt = 0; nt < 4; ++nt){
            union { unsigned u[4]; bf16x8 v; } pbu;
            #pragma unroll
            for (int t = 0; t < 4; ++t){
                int addr = (t >> 1) ? a1 : a0;
                unsigned lo2 = (unsigned)__builtin_amdgcn_ds_bpermute(addr, (int)pk[nt][2 * ks][t & 1]);
                unsigned hi2 = (unsigned)__builtin_amdgcn_ds_bpermute(addr, (int)pk[nt][2 * ks + 1][t & 1]);
                pbu.u[t] = sel ? hi2 : lo2;
            }
            pb[nt] = pbu.v;
        }
        __builtin_amdgcn_s_setprio(1);
        #pragma unroll
        for (int nt = 0; nt < 4; ++nt)
            #pragma unroll
            for (int mt = 0; mt < 2; ++mt)
                acco[mt][nt] = __builtin_amdgcn_mfma_f32_16x16x32_bf16(va[mt], pb[nt], acco[mt][nt], 0, 0, 0);
        __builtin_amdgcn_s_setprio(0);
    }

    // store: row = d = 16mt+4g+r, col = q = 16nt+c
    #pragma unroll
    for (int mt = 0; mt < 2; ++mt)
        #pragma unroll
        for (int nt = 0; nt < 4; ++nt){
            int q = 16 * nt + c;
            if (q < 49){
                u16x4 o;
                #pragma unroll
                for (int r = 0; r < 4; ++r) o[r] = f2b(acco[mt][nt][r] * inv[nt]);
                *(u16x4*)(out + (size_t)(w * 49 + q) * 384 + h * 32 + 16 * mt + 4 * g) = o;
            }
        }
}

extern "C" void kernel_launch(void* const* d_in, const int* in_sizes, int n_in,
                              void* d_out, int out_size, void* d_ws, size_t ws_size,
                              hipStream_t stream) {
    const float* x      = (const float*)d_in[0];
    const float* rpb    = (const float*)d_in[1];
    const float* qkv_w  = (const float*)d_in[2];
    const float* qkv_b  = (const float*)d_in[3];
    const float* proj_w = (const float*)d_in[4];
    const float* proj_b = (const float*)d_in[5];
    const float* fc1_w  = (const float*)d_in[6];
    const float* fc1_b  = (const float*)d_in[7];
    const float* fc2_w  = (const float*)d_in[8];
    const float* fc2_b  = (const float*)d_in[9];
    const float* n1w    = (const float*)d_in[10];
    const float* n1b    = (const float*)d_in[11];
    const float* n2w    = (const float*)d_in[12];
    const float* n2b    = (const float*)d_in[13];

    char* ws = (char*)d_ws;
    uint16_t* winA  = (uint16_t*)ws;                      // 50176x384 bf16 (win / attn-out / ln2-out)
    uint16_t* qkB   = (uint16_t*)(ws + 38535168);         // 50176x1152 bf16 (qkv), later: x2b + hidden
    uint16_t* x2b   = qkB;                                // 50176x384 bf16 (x + attn, pixel order)
    uint16_t* hid   = (uint16_t*)(ws + 77070336);         // 25088x1536 bf16 (per chunk)
    uint16_t* wbuf  = (uint16_t*)(ws + 154140672);
    uint16_t* w_qkv  = wbuf;
    uint16_t* w_proj = wbuf + 442368;
    uint16_t* w_fc1  = w_proj + 147456;
    uint16_t* w_fc2  = w_fc1 + 589824;
    float*    bmtab  = (float*)(ws + 157679616);          // 4x12x64x64 fp32 = 786 KB

    // weights->bf16 + bm table + LN1/shift/partition in one launch
    init_kernel<<<19504, 256, 0, stream>>>(qkv_w, proj_w, fc1_w, fc2_w,
                                           w_qkv, w_proj, w_fc1, w_fc2,
                                           rpb, bmtab, x, n1w, n1b, winA);

    // QKV GEMM -> natural [row][1152], q pre-scaled
    gemm_bt<5><<<392 * 9, 256, 0, stream>>>(winA, w_qkv, qkv_b, qkB, nullptr, nullptr, 1152, 384, 0);

    // windowed attention (MFMA + bm table)
    attn_mfma<<<3072, 256, 0, stream>>>(qkB, bmtab, winA);

    // proj GEMM + window-reverse/unshift + shortcut -> x2b (bf16, pixel order)
    gemm_bt<6><<<392 * 3, 256, 0, stream>>>(winA, w_proj, proj_b, x2b, x, nullptr, 384, 384, 0);

    // LN2 (bf16 in) -> winA
    ln2_kernel<<<12544, 256, 0, stream>>>(x2b, n2w, n2b, winA);

    // MLP, 2 row-chunks of 25088; fc2 uses 64x128 tiles
    for (int c2 = 0; c2 < 2; ++c2){
        size_t r0 = (size_t)c2 * 25088;
        gemm_bt<1><<<196 * 12, 256, 0, stream>>>(winA + r0 * 384, w_fc1, fc1_b, hid, nullptr, nullptr, 1536, 384, 0);
        gemm_fc2<<<392 * 3, 256, 0, stream>>>(hid, w_fc2, fc2_b, (float*)d_out + r0 * 384, x2b + r0 * 384, 1536);
    }
}

// Round 18
// 345.924 us; speedup vs baseline: 1.1130x; 1.1130x over previous
//
#include <hip/hip_runtime.h>
#include <cstdint>
#include <cstddef>

#define AS1 __attribute__((address_space(1)))
#define AS3 __attribute__((address_space(3)))

typedef __attribute__((ext_vector_type(8))) short bf16x8;
typedef __attribute__((ext_vector_type(4))) short short4v;
typedef __attribute__((ext_vector_type(8))) unsigned short u16x8;
typedef __attribute__((ext_vector_type(4))) float f32x4;
typedef __attribute__((ext_vector_type(4))) unsigned short u16x4;

__device__ __forceinline__ float b2f(uint16_t u){ return __uint_as_float(((uint32_t)u) << 16); }
__device__ __forceinline__ uint16_t f2b(float f){
    uint32_t u = __float_as_uint(f);
    return (uint16_t)((u + 0x7fffu + ((u >> 16) & 1u)) >> 16);
}

// window-order row r  ->  pixel index (window reverse + unshift / shift+partition gather)
__device__ __forceinline__ int pixof(int r){
    int w  = r / 49, t = r - w * 49;
    int wh = w >> 5, ww = w & 31;
    int th = t / 7,  tw = t - th * 7;
    int hp = wh * 7 + th + 3; if (hp >= 224) hp -= 224;
    int wp = ww * 7 + tw + 3; if (wp >= 224) wp -= 224;
    return hp * 224 + wp;
}

// --- init über-kernel: weights fp32->bf16 (blocks 0..6911), bias/mask table
// (6912..6959), LN1+shift+window-partition (6960..19503) -------------------
__global__ __launch_bounds__(256) void init_kernel(
        const float* __restrict__ a0, const float* __restrict__ a1,
        const float* __restrict__ a2, const float* __restrict__ a3,
        uint16_t* __restrict__ o0, uint16_t* __restrict__ o1,
        uint16_t* __restrict__ o2, uint16_t* __restrict__ o3,
        const float* __restrict__ rpb, float* __restrict__ bm,
        const float* __restrict__ x, const float* __restrict__ n1w,
        const float* __restrict__ n1b, uint16_t* __restrict__ win){
    int b = blockIdx.x;
    if (b >= 6960){
        int wave = threadIdx.x >> 6, lane = threadIdx.x & 63;
        int r = (b - 6960) * 4 + wave;
        const float* row = x + (size_t)pixof(r) * 384;
        float a[6];
        #pragma unroll
        for (int i = 0; i < 6; ++i) a[i] = row[lane * 6 + i];
        float s = 0.f, q = 0.f;
        #pragma unroll
        for (int i = 0; i < 6; ++i){ s += a[i]; q += a[i] * a[i]; }
        #pragma unroll
        for (int o = 32; o; o >>= 1){ s += __shfl_xor(s, o); q += __shfl_xor(q, o); }
        float mu   = s * (1.f / 384.f);
        float var  = q * (1.f / 384.f) - mu * mu;
        float rstd = rsqrtf(var + 1e-5f);
        uint16_t* orow = win + (size_t)r * 384;
        #pragma unroll
        for (int i = 0; i < 6; ++i){
            int c = lane * 6 + i;
            orow[c] = f2b((a[i] - mu) * rstd * n1w[c] + n1b[c]);
        }
        return;
    }
    if (b >= 6912){
        int th = b - 6912;                // 0..47 = type*12 + h
        int type = th / 12, h = th - (th / 12) * 12;
        int eh = type >> 1, ew = type & 1;
        for (int idx = threadIdx.x; idx < 4096; idx += 256){
            int q = idx >> 6, kt = idx & 63;
            float v = 0.f;
            if (q < 49 && kt < 49){
                int ih = q / 7,  iw = q - 7 * (q / 7);
                int jh = kt / 7, jw = kt - 7 * (kt / 7);
                v = rpb[((ih - jh + 6) * 13 + (iw - jw + 6)) * 12 + h];
                int ri = (eh ? (ih < 4 ? 1 : 2) : 0) * 3 + (ew ? (iw < 4 ? 1 : 2) : 0);
                int rj = (eh ? (jh < 4 ? 1 : 2) : 0) * 3 + (ew ? (jw < 4 ? 1 : 2) : 0);
                if (ri != rj) v -= 100.f;
            }
            bm[(size_t)th * 4096 + idx] = v;
        }
        return;
    }
    const float* src; uint16_t* dst; int base;
    if (b < 1728)      { src = a0; dst = o0; base = b; }
    else if (b < 2304) { src = a1; dst = o1; base = b - 1728; }
    else if (b < 4608) { src = a2; dst = o2; base = b - 2304; }
    else               { src = a3; dst = o3; base = b - 4608; }
    int i = base * 256 + threadIdx.x;
    dst[i] = f2b(src[i]);
}

// ---------------- LN2: bf16 in (vectorized u16x8, 48 active lanes) -> bf16 -----
__global__ __launch_bounds__(256) void ln2_kernel(const uint16_t* __restrict__ in,
        const float* __restrict__ g, const float* __restrict__ b, uint16_t* __restrict__ out){
    int wave = threadIdx.x >> 6, lane = threadIdx.x & 63;
    int r = blockIdx.x * 4 + wave;
    u16x8 v8 = {0,0,0,0,0,0,0,0};
    if (lane < 48) v8 = *(const u16x8*)(in + (size_t)r * 384 + lane * 8);
    float a[8];
    float s = 0.f, q = 0.f;
    #pragma unroll
    for (int i = 0; i < 8; ++i){ a[i] = b2f(v8[i]); s += a[i]; q += a[i] * a[i]; }
    #pragma unroll
    for (int o = 32; o; o >>= 1){ s += __shfl_xor(s, o); q += __shfl_xor(q, o); }
    float mu   = s * (1.f / 384.f);
    float var  = q * (1.f / 384.f) - mu * mu;
    float rstd = rsqrtf(var + 1e-5f);
    if (lane < 48){
        u16x8 o8;
        #pragma unroll
        for (int i = 0; i < 8; ++i){
            int c = lane * 8 + i;
            o8[i] = f2b((a[i] - mu) * rstd * g[c] + b[c]);
        }
        *(u16x8*)(out + (size_t)r * 384 + lane * 8) = o8;
    }
}

// ---------------- GEMM: C = A(MxK) * B(NxK)^T + bias, BK=64 single-buffer -------
// 128x128 tile, 4 waves (2x2), per-wave 4x4 16x16 frags, K-step 64.
// LDS rows are 128 B with 8-slot XOR swizzle (2-way banks = free), staged via
// lane-pure pre-swizzled global source (rule #21). 32 KB LDS -> ~3 blocks/CU.
// EPI 1: bf16 out + exact GELU (fc1).
// EPI 5: bf16 out natural [row][N], cols<384 scaled (qkv).
// EPI 6: bf16 x2 out, pixof-permuted, + fp32 shortcut xres (proj).
// EPI 7: fp32 out = bf16 x2b + acc + bias, write-only (fc2 final).
template<int EPI>
__global__ __launch_bounds__(256, 2) void gemm_bt(
        const uint16_t* __restrict__ A, const uint16_t* __restrict__ B,
        const float* __restrict__ bias, void* __restrict__ outp,
        const float* __restrict__ xres, const uint16_t* __restrict__ xb,
        int N, int K, int row0)
{
    __shared__ alignas(16) uint16_t lA[128 * 64];
    __shared__ alignas(16) uint16_t lB[128 * 64];
    int tid  = threadIdx.x;
    int lane = tid & 63, wave = tid >> 6;

    // XCD-chunked bijective swizzle: same-bm tiles land on one XCD (A-panel L2 reuse)
    int nwg = gridDim.x, bid = blockIdx.x;
    int q8 = nwg >> 3, r8 = nwg & 7;
    int xcd = bid & 7, idx = bid >> 3;
    int wg = (xcd < r8 ? xcd * (q8 + 1) : r8 * (q8 + 1) + (xcd - r8) * q8) + idx;

    int nt = N >> 7;
    int bm = wg / nt, bn = wg - bm * nt;
    int wr = wave >> 1, wc = wave & 1;
    int fr = lane & 15, kc = lane >> 4;

    int srow = wave * 32 + (lane >> 3);
    int cs   = (lane & 7) ^ ((lane >> 3) & 7);
    const uint16_t* gA = A + (size_t)(bm * 128 + srow) * K + cs * 8;
    const uint16_t* gB = B + (size_t)(bn * 128 + srow) * K + cs * 8;

    int aoff[4], boff[4];
    #pragma unroll
    for (int m = 0; m < 4; ++m){
        int row = wr * 64 + m * 16 + fr;
        aoff[m] = row * 128 + ((kc * 16) ^ ((row & 7) << 4));
        int rowB = wc * 64 + m * 16 + fr;
        boff[m] = rowB * 128 + ((kc * 16) ^ ((rowB & 7) << 4));
    }

    f32x4 acc[4][4] = {};
    const int NT = K >> 6;
    for (int t = 0; t < NT; ++t){
        int k0 = t << 6;
        #pragma unroll
        for (int it = 0; it < 4; ++it){
            __builtin_amdgcn_global_load_lds((const AS1 void*)(gA + k0 + (size_t)it * 8 * K),
                (AS3 void*)((AS3 char*)lA + wave * 4096 + it * 1024), 16, 0, 0);
            __builtin_amdgcn_global_load_lds((const AS1 void*)(gB + k0 + (size_t)it * 8 * K),
                (AS3 void*)((AS3 char*)lB + wave * 4096 + it * 1024), 16, 0, 0);
        }
        __syncthreads();

        #pragma unroll
        for (int ks = 0; ks < 2; ++ks){
            bf16x8 af[4], bv[4];
            #pragma unroll
            for (int m = 0; m < 4; ++m)
                af[m] = *(const bf16x8*)((const char*)lA + (aoff[m] ^ (ks << 6)));
            #pragma unroll
            for (int n = 0; n < 4; ++n)
                bv[n] = *(const bf16x8*)((const char*)lB + (boff[n] ^ (ks << 6)));
            #pragma unroll
            for (int m = 0; m < 4; ++m)
                #pragma unroll
                for (int n = 0; n < 4; ++n)
                    acc[m][n] = __builtin_amdgcn_mfma_f32_16x16x32_bf16(af[m], bv[n], acc[m][n], 0, 0, 0);
        }
        __syncthreads();
    }

    int colb = bn * 128 + wc * 64 + fr;
    int rowb = bm * 128 + wr * 64 + ((lane >> 4) << 2);
    float bvv[4];
    #pragma unroll
    for (int n = 0; n < 4; ++n) bvv[n] = bias[colb + n * 16];

    if constexpr (EPI == 1 || EPI == 5){
        uint16_t* out = (uint16_t*)outp;
        #pragma unroll
        for (int m = 0; m < 4; ++m)
            #pragma unroll
            for (int rg = 0; rg < 4; ++rg){
                size_t rr = (size_t)(rowb + m * 16 + rg) * N;
                #pragma unroll
                for (int n = 0; n < 4; ++n){
                    int col = colb + n * 16;
                    float v = acc[m][n][rg] + bvv[n];
                    if constexpr (EPI == 1) v = 0.5f * v * (1.f + erff(v * 0.7071067811865475f));
                    if constexpr (EPI == 5){ if (col < 384) v *= 0.1767766952966369f; }
                    out[rr + col] = f2b(v);
                }
            }
    } else if constexpr (EPI == 6){
        uint16_t* out = (uint16_t*)outp;
        #pragma unroll
        for (int m = 0; m < 4; ++m)
            #pragma unroll
            for (int rg = 0; rg < 4; ++rg){
                int r = row0 + rowb + m * 16 + rg;
                size_t pb = (size_t)pixof(r) * 384;
                #pragma unroll
                for (int n = 0; n < 4; ++n){
                    int c = colb + n * 16;
                    out[pb + c] = f2b(xres[pb + c] + acc[m][n][rg] + bvv[n]);
                }
            }
    } else { // EPI == 7
        float* out = (float*)outp;
        #pragma unroll
        for (int m = 0; m < 4; ++m)
            #pragma unroll
            for (int rg = 0; rg < 4; ++rg){
                size_t rb2 = (size_t)(rowb + m * 16 + rg) * 384;
                #pragma unroll
                for (int n = 0; n < 4; ++n){
                    int c = colb + n * 16;
                    out[rb2 + c] = b2f(xb[rb2 + c]) + acc[m][n][rg] + bvv[n];
                }
            }
    }
}

// ------- fc2 GEMM: 64x128 tile (finer grid for K=1536 packing), BK=64 ----------
// 4 waves as 1M x 4N strips: wave = rows[0:64] x cols[wave*32 : wave*32+32],
// acc[4][2]. Same staging/XOR-swizzle mechanics as gemm_bt.
// out fp32 = bf16 xb + acc + bias (write-only d_out).
__global__ __launch_bounds__(256, 2) void gemm_fc2(
        const uint16_t* __restrict__ A, const uint16_t* __restrict__ B,
        const float* __restrict__ bias, float* __restrict__ out,
        const uint16_t* __restrict__ xb, int K)
{
    __shared__ alignas(16) uint16_t lA[64 * 64];
    __shared__ alignas(16) uint16_t lB[128 * 64];
    int tid  = threadIdx.x;
    int lane = tid & 63, wave = tid >> 6;

    int nwg = gridDim.x, bid = blockIdx.x;
    int q8 = nwg >> 3, r8 = nwg & 7;
    int xcd = bid & 7, idx = bid >> 3;
    int wg = (xcd < r8 ? xcd * (q8 + 1) : r8 * (q8 + 1) + (xcd - r8) * q8) + idx;

    int bm = wg / 3, bn = wg - bm * 3;    // N = 384 -> 3 col-tiles of 128
    int fr = lane & 15, kc = lane >> 4;

    int cs = (lane & 7) ^ ((lane >> 3) & 7);
    const uint16_t* gA = A + (size_t)(bm * 64 + wave * 16 + (lane >> 3)) * K + cs * 8;
    const uint16_t* gB = B + (size_t)(bn * 128 + wave * 32 + (lane >> 3)) * K + cs * 8;

    int aoff[4], boff[2];
    #pragma unroll
    for (int m = 0; m < 4; ++m){
        int row = m * 16 + fr;
        aoff[m] = row * 128 + ((kc * 16) ^ ((row & 7) << 4));
    }
    #pragma unroll
    for (int n = 0; n < 2; ++n){
        int rowB = wave * 32 + n * 16 + fr;
        boff[n] = rowB * 128 + ((kc * 16) ^ ((rowB & 7) << 4));
    }

    f32x4 acc[4][2] = {};
    const int NT = K >> 6;
    for (int t = 0; t < NT; ++t){
        int k0 = t << 6;
        #pragma unroll
        for (int it = 0; it < 2; ++it)
            __builtin_amdgcn_global_load_lds((const AS1 void*)(gA + k0 + (size_t)it * 8 * K),
                (AS3 void*)((AS3 char*)lA + wave * 2048 + it * 1024), 16, 0, 0);
        #pragma unroll
        for (int it = 0; it < 4; ++it)
            __builtin_amdgcn_global_load_lds((const AS1 void*)(gB + k0 + (size_t)it * 8 * K),
                (AS3 void*)((AS3 char*)lB + wave * 4096 + it * 1024), 16, 0, 0);
        __syncthreads();

        #pragma unroll
        for (int ks = 0; ks < 2; ++ks){
            bf16x8 af[4], bv[2];
            #pragma unroll
            for (int m = 0; m < 4; ++m)
                af[m] = *(const bf16x8*)((const char*)lA + (aoff[m] ^ (ks << 6)));
            #pragma unroll
            for (int n = 0; n < 2; ++n)
                bv[n] = *(const bf16x8*)((const char*)lB + (boff[n] ^ (ks << 6)));
            #pragma unroll
            for (int m = 0; m < 4; ++m)
                #pragma unroll
                for (int n = 0; n < 2; ++n)
                    acc[m][n] = __builtin_amdgcn_mfma_f32_16x16x32_bf16(af[m], bv[n], acc[m][n], 0, 0, 0);
        }
        __syncthreads();
    }

    int colb = bn * 128 + wave * 32 + fr;
    int rowb = bm * 64 + kc * 4;
    float bvv[2] = { bias[colb], bias[colb + 16] };
    #pragma unroll
    for (int m = 0; m < 4; ++m)
        #pragma unroll
        for (int rg = 0; rg < 4; ++rg){
            size_t rb2 = (size_t)(rowb + m * 16 + rg) * 384;
            #pragma unroll
            for (int n = 0; n < 2; ++n){
                int c = colb + n * 16;
                out[rb2 + c] = b2f(xb[rb2 + c]) + acc[m][n][rg] + bvv[n];
            }
        }
}

// ---------------- MFMA windowed attention: one wave per (window, head) ----------------
// qkv: [50176][1152] bf16, q pre-scaled.  bm: bias+mask table (C-operand of QK^T).
// V: global -> regs (early, T14) -> scalar-transpose LDS [32][68] -> b64 row reads.
__global__ __launch_bounds__(256) void attn_mfma(const uint16_t* __restrict__ qkv,
        const float* __restrict__ bm, uint16_t* __restrict__ out)
{
    __shared__ uint16_t vtl[4][32][68];   // [d][t] padded t->68 (odd 8B stride: 4-way-free b64 reads)
    int wv = threadIdx.x >> 6, lane = threadIdx.x & 63;
    int p = blockIdx.x * 4 + wv;
    int w = p / 12, h = p - w * 12;
    int c = lane & 15, g = lane >> 4;
    const uint16_t* base = qkv + (size_t)(w * 49) * 1152 + h * 32;

    // V global loads issued early (T14 async split)
    u16x8 vreg[4];
    #pragma unroll
    for (int it = 0; it < 4; ++it){
        int u = it * 64 + lane;           // u = t*4 + dq
        int t = u >> 2, dq = u & 3;
        u16x8 v8 = {0,0,0,0,0,0,0,0};
        if (t < 49) v8 = *(const u16x8*)(base + (size_t)t * 1152 + 768 + dq * 8);
        vreg[it] = v8;
    }

    // Q (B-frag) and K (A-frag): 16B contiguous per lane
    bf16x8 qf[4], kf[4];
    #pragma unroll
    for (int nt = 0; nt < 4; ++nt) qf[nt] = *(const bf16x8*)(base + (size_t)(16 * nt + c) * 1152 + g * 8);
    #pragma unroll
    for (int mt = 0; mt < 4; ++mt) kf[mt] = *(const bf16x8*)(base + (size_t)(16 * mt + c) * 1152 + 384 + g * 8);

    // S^T = K * Q^T + biasmask(C-operand): row = kt = 16mt+4g+r, col = q = 16nt+c
    int wh = w >> 5, ww = w & 31;
    int type = ((wh == 31) << 1) | (ww == 31);
    const float* bmp = bm + (size_t)(type * 12 + h) * 4096;
    f32x4 sv[4][4];
    __builtin_amdgcn_s_setprio(1);
    #pragma unroll
    for (int mt = 0; mt < 4; ++mt)
        #pragma unroll
        for (int nt = 0; nt < 4; ++nt){
            f32x4 cb = *(const f32x4*)(bmp + (16 * nt + c) * 64 + 16 * mt + 4 * g);
            sv[mt][nt] = __builtin_amdgcn_mfma_f32_16x16x32_bf16(kf[mt], qf[nt], cb, 0, 0, 0);
        }
    __builtin_amdgcn_s_setprio(0);

    // V -> LDS scalar transpose (proven path)
    #pragma unroll
    for (int it = 0; it < 4; ++it){
        int u = it * 64 + lane;
        int t = u >> 2, dq = u & 3;
        #pragma unroll
        for (int j = 0; j < 8; ++j) vtl[wv][dq * 8 + j][t] = vreg[it][j];
    }

    // kt >= 49 mask (only mt=3 rows: kt = 48+4g+r)
    #pragma unroll
    for (int nt = 0; nt < 4; ++nt)
        #pragma unroll
        for (int r = 0; r < 4; ++r)
            if (4 * g + r >= 1) sv[3][nt][r] = -1e9f;

    // softmax over kt (rows of S^T)
    float inv[4];
    #pragma unroll
    for (int nt = 0; nt < 4; ++nt){
        float mx = -1e30f;
        #pragma unroll
        for (int mt = 0; mt < 4; ++mt)
            #pragma unroll
            for (int r = 0; r < 4; ++r) mx = fmaxf(mx, sv[mt][nt][r]);
        mx = fmaxf(mx, __shfl_xor(mx, 16));
        mx = fmaxf(mx, __shfl_xor(mx, 32));
        float sum = 0.f;
        #pragma unroll
        for (int mt = 0; mt < 4; ++mt)
            #pragma unroll
            for (int r = 0; r < 4; ++r){
                float e = __expf(sv[mt][nt][r] - mx);
                sv[mt][nt][r] = e; sum += e;
            }
        sum += __shfl_xor(sum, 16);
        sum += __shfl_xor(sum, 32);
        inv[nt] = 1.f / sum;
    }

    // pack P to bf16 pairs
    unsigned pk[4][4][2];
    #pragma unroll
    for (int nt = 0; nt < 4; ++nt)
        #pragma unroll
        for (int mt = 0; mt < 4; ++mt)
            #pragma unroll
            for (int pr = 0; pr < 2; ++pr)
                pk[nt][mt][pr] = (unsigned)f2b(sv[mt][nt][2 * pr]) |
                                 ((unsigned)f2b(sv[mt][nt][2 * pr + 1]) << 16);

    // relayout P^T(C-layout) -> B-frags via ds_bpermute
    int a0 = (c + 16 * (2 * (g & 1))) * 4;
    int a1 = a0 + 64;
    int sel = g >> 1;

    f32x4 acco[2][4] = {};
    #pragma unroll
    for (int ks = 0; ks < 2; ++ks){
        bf16x8 va[2];
        #pragma unroll
        for (int mt = 0; mt < 2; ++mt){
            short4v lo = *(const short4v*)&vtl[wv][mt * 16 + c][ks * 32 + g * 8];
            short4v hi = *(const short4v*)&vtl[wv][mt * 16 + c][ks * 32 + g * 8 + 4];
            bf16x8 t;
            t[0] = lo[0]; t[1] = lo[1]; t[2] = lo[2]; t[3] = lo[3];
            t[4] = hi[0]; t[5] = hi[1]; t[6] = hi[2]; t[7] = hi[3];
            va[mt] = t;
        }
        bf16x8 pb[4];
        #pragma unroll
        for (int nt = 0; nt < 4; ++nt){
            union { unsigned u[4]; bf16x8 v; } pbu;
            #pragma unroll
            for (int t = 0; t < 4; ++t){
                int addr = (t >> 1) ? a1 : a0;
                unsigned lo2 = (unsigned)__builtin_amdgcn_ds_bpermute(addr, (int)pk[nt][2 * ks][t & 1]);
                unsigned hi2 = (unsigned)__builtin_amdgcn_ds_bpermute(addr, (int)pk[nt][2 * ks + 1][t & 1]);
                pbu.u[t] = sel ? hi2 : lo2;
            }
            pb[nt] = pbu.v;
        }
        __builtin_amdgcn_s_setprio(1);
        #pragma unroll
        for (int nt = 0; nt < 4; ++nt)
            #pragma unroll
            for (int mt = 0; mt < 2; ++mt)
                acco[mt][nt] = __builtin_amdgcn_mfma_f32_16x16x32_bf16(va[mt], pb[nt], acco[mt][nt], 0, 0, 0);
        __builtin_amdgcn_s_setprio(0);
    }

    // store: row = d = 16mt+4g+r, col = q = 16nt+c
    #pragma unroll
    for (int mt = 0; mt < 2; ++mt)
        #pragma unroll
        for (int nt = 0; nt < 4; ++nt){
            int q = 16 * nt + c;
            if (q < 49){
                u16x4 o;
                #pragma unroll
                for (int r = 0; r < 4; ++r) o[r] = f2b(acco[mt][nt][r] * inv[nt]);
                *(u16x4*)(out + (size_t)(w * 49 + q) * 384 + h * 32 + 16 * mt + 4 * g) = o;
            }
        }
}

extern "C" void kernel_launch(void* const* d_in, const int* in_sizes, int n_in,
                              void* d_out, int out_size, void* d_ws, size_t ws_size,
                              hipStream_t stream) {
    const float* x      = (const float*)d_in[0];
    const float* rpb    = (const float*)d_in[1];
    const float* qkv_w  = (const float*)d_in[2];
    const float* qkv_b  = (const float*)d_in[3];
    const float* proj_w = (const float*)d_in[4];
    const float* proj_b = (const float*)d_in[5];
    const float* fc1_w  = (const float*)d_in[6];
    const float* fc1_b  = (const float*)d_in[7];
    const float* fc2_w  = (const float*)d_in[8];
    const float* fc2_b  = (const float*)d_in[9];
    const float* n1w    = (const float*)d_in[10];
    const float* n1b    = (const float*)d_in[11];
    const float* n2w    = (const float*)d_in[12];
    const float* n2b    = (const float*)d_in[13];

    char* ws = (char*)d_ws;
    uint16_t* winA  = (uint16_t*)ws;                      // 50176x384 bf16 (win / attn-out / ln2-out)
    uint16_t* qkB   = (uint16_t*)(ws + 38535168);         // 50176x1152 bf16 (qkv), later: x2b + hidden
    uint16_t* x2b   = qkB;                                // 50176x384 bf16 (x + attn, pixel order)
    uint16_t* hid   = (uint16_t*)(ws + 77070336);         // 25088x1536 bf16 (per chunk)
    uint16_t* wbuf  = (uint16_t*)(ws + 154140672);
    uint16_t* w_qkv  = wbuf;
    uint16_t* w_proj = wbuf + 442368;
    uint16_t* w_fc1  = w_proj + 147456;
    uint16_t* w_fc2  = w_fc1 + 589824;
    float*    bmtab  = (float*)(ws + 157679616);          // 4x12x64x64 fp32 = 786 KB

    // weights->bf16 + bm table + LN1/shift/partition in one launch
    init_kernel<<<19504, 256, 0, stream>>>(qkv_w, proj_w, fc1_w, fc2_w,
                                           w_qkv, w_proj, w_fc1, w_fc2,
                                           rpb, bmtab, x, n1w, n1b, winA);

    // QKV GEMM -> natural [row][1152], q pre-scaled
    gemm_bt<5><<<392 * 9, 256, 0, stream>>>(winA, w_qkv, qkv_b, qkB, nullptr, nullptr, 1152, 384, 0);

    // windowed attention (MFMA + bm table)
    attn_mfma<<<3072, 256, 0, stream>>>(qkB, bmtab, winA);

    // proj GEMM + window-reverse/unshift + shortcut -> x2b (bf16, pixel order)
    gemm_bt<6><<<392 * 3, 256, 0, stream>>>(winA, w_proj, proj_b, x2b, x, nullptr, 384, 384, 0);

    // LN2 (bf16 in) -> winA
    ln2_kernel<<<12544, 256, 0, stream>>>(x2b, n2w, n2b, winA);

    // MLP, 2 row-chunks of 25088; fc2 uses 64x128 tiles (1176 blocks: 9% tail vs 30%)
    for (int c2 = 0; c2 < 2; ++c2){
        size_t r0 = (size_t)c2 * 25088;
        gemm_bt<1><<<196 * 12, 256, 0, stream>>>(winA + r0 * 384, w_fc1, fc1_b, hid, nullptr, nullptr, 1536, 384, 0);
        gemm_fc2<<<392 * 3, 256, 0, stream>>>(hid, w_fc2, fc2_b, (float*)d_out + r0 * 384, x2b + r0 * 384, 1536);
    }
}